// Round 1
// baseline (2655.935 us; speedup 1.0000x reference)
//
#include <hip/hip_runtime.h>

#define L_PAD 8192
#define HS    25
#define ES    50
#define G4    100   // 4*H
#define LOG2E 1.44269504088896340736f

// -------- workspace layout --------
// zs2   : float2[2][L_PAD*50]   packed gate preacts: zs2[d][t*50+j] = (z[j], z[j+50])
// wstar : float2[2][50]         h* @ Wh, same packing
// cstar : float [2][25]         frozen cell state
// total ~6.56 MB

__device__ __forceinline__ float rl_f(float v, int lane) {
    return __int_as_float(__builtin_amdgcn_readlane(__float_as_int(v), lane));
}
__device__ __forceinline__ float fast_sigmoid(float x) {
    return __builtin_amdgcn_rcpf(1.f + __builtin_amdgcn_exp2f(x * (-LOG2E)));
}
__device__ __forceinline__ float fast_tanh(float x) {
    // 2*sigmoid(2x) - 1
    return fmaf(__builtin_amdgcn_rcpf(1.f + __builtin_amdgcn_exp2f(x * (-2.f * LOG2E))), 2.f, -1.f);
}

// ---------------- kernel 1: pre-activations (parallel) ----------------
__global__ __launch_bounds__(64) void k_pre(
    const int* __restrict__ tok, const int* __restrict__ plen,
    const float* __restrict__ Ef, const float* __restrict__ Wif, const float* __restrict__ bf,
    const float* __restrict__ Eb, const float* __restrict__ Wib, const float* __restrict__ bb,
    float2* __restrict__ zs2)
{
    const int b = blockIdx.x;
    const int d = b & 1;
    const int t = b >> 1;
    const int j = threadIdx.x;
    const int len = *plen;

    // backward direction token stream: rev[t] = sentence[len-1-t] for t<len,
    // else sentence[L-1-(t-len)]   (== roll(flip(sentence), -(L-len)))
    int src;
    if (d == 0) src = t;
    else        src = (t < len) ? (len - 1 - t) : (L_PAD - 1 - (t - len));
    const int token = tok[src];

    const float* __restrict__ E  = d ? Eb  : Ef;
    const float* __restrict__ Wi = d ? Wib : Wif;
    const float* __restrict__ bs = d ? bb  : bf;

    __shared__ float e[ES];
    if (j < ES) e[j] = E[(size_t)token * ES + j];
    __syncthreads();
    if (j >= 50) return;

    float ax = bs[j], ay = bs[j + 50];
    float bx = 0.f,  by = 0.f;
    #pragma unroll
    for (int k = 0; k < ES; k += 2) {
        float e0 = e[k], e1 = e[k + 1];
        ax = fmaf(e0, Wi[k * G4 + j],            ax);
        ay = fmaf(e0, Wi[k * G4 + j + 50],       ay);
        bx = fmaf(e1, Wi[(k + 1) * G4 + j],      bx);
        by = fmaf(e1, Wi[(k + 1) * G4 + j + 50], by);
    }
    zs2[(size_t)d * (L_PAD * 50) + t * 50 + j] = make_float2(ax + bx, ay + by);
}

// ---------------- kernel 2: the serial recurrence (latency-bound) ----------------
// one wave per direction. lane j in [0,50): gates (j, j+50).
//   lanes 0..24  -> (i_k, g_k),  lanes 25..49 -> (f_k, o_k)
// h broadcast via v_readlane (SGPR operand into the FMAs, no LDS round trip).
__global__ __launch_bounds__(64) void k_seq(
    const float* __restrict__ Whf, const float* __restrict__ Whb,
    const int* __restrict__ plen,
    const float2* __restrict__ zs2_all,
    float* __restrict__ out,
    float2* __restrict__ wstar, float* __restrict__ cstar)
{
    const int d = blockIdx.x;
    const int j = threadIdx.x;
    const int len = *plen;
    const float* __restrict__ Wh = d ? Whb : Whf;
    const float2* __restrict__ z = zs2_all + (size_t)d * (L_PAD * 50);
    const int jj = (j < 50) ? j : 0;

    // Wh columns for my two gates, packed: 50 VGPRs
    float2 W[HS];
    #pragma unroll
    for (int k = 0; k < HS; ++k)
        W[k] = make_float2(Wh[k * G4 + jj], Wh[k * G4 + jj + 50]);

    // branch-free activation constants: acc.y is tanh for lanes<25, sigmoid otherwise
    const bool  isG = (j < 25);
    const float my = isG ? (-2.f * LOG2E) : (-LOG2E);
    const float ca = isG ? 2.f : 1.f;
    const float cb = isG ? -1.f : 0.f;

    float c = 0.f, h = 0.f;   // lanes 0..24 carry state; others stay 0/garbage (unused)
    float2 zc = z[jj];
    float2 zn = z[50 + jj];
    float* outp = out + d * HS + j;   // stride 50 floats per step

    for (int t = 0; t < len; ++t) {
        int tp = t + 2; if (tp >= L_PAD) tp = L_PAD - 1;
        float2 zf = z[tp * 50 + jj];                     // prefetch dist 2

        // z + h @ Wh  (4 accumulator chains to cut FMA dep latency)
        float2 a[4] = {zc, make_float2(0.f, 0.f), make_float2(0.f, 0.f), make_float2(0.f, 0.f)};
        #pragma unroll
        for (int k = 0; k < HS; ++k) {
            float hk = rl_f(h, k);                       // wave-uniform broadcast
            a[k & 3].x = fmaf(hk, W[k].x, a[k & 3].x);
            a[k & 3].y = fmaf(hk, W[k].y, a[k & 3].y);
        }
        float px = (a[0].x + a[1].x) + (a[2].x + a[3].x);
        float py = (a[0].y + a[1].y) + (a[2].y + a[3].y);

        float sa = fast_sigmoid(px);                     // i (lanes<25) / f (lanes>=25)
        float ry = __builtin_amdgcn_rcpf(1.f + __builtin_amdgcn_exp2f(py * my));
        float sb = fmaf(ry, ca, cb);                     // g=tanh (lanes<25) / o=sigmoid

        float f_ = __shfl(sa, j + 25);                   // lane k reads lane k+25
        float o_ = __shfl(sb, j + 25);
        float nc = fmaf(f_, c, sa * sb);                 // f*c + i*g
        float nh = o_ * fast_tanh(nc);
        if (j < 25) {
            c = nc; h = nh;
            outp[t * 50] = nh;                           // out[t*50 + d*25 + j]
        }
        zc = zn; zn = zf;
    }

    // epilogue: w* = h* @ Wh (packed) and c* for the frozen tail
    float2 a = make_float2(0.f, 0.f);
    #pragma unroll
    for (int k = 0; k < HS; ++k) {
        float hk = rl_f(h, k);
        a.x = fmaf(hk, W[k].x, a.x);
        a.y = fmaf(hk, W[k].y, a.y);
    }
    if (j < 50) wstar[d * 50 + j] = a;
    if (j < 25) cstar[d * HS + j] = c;
}

// ---------------- kernel 3: frozen-carry tail (parallel) ----------------
// for t >= len: nh_t = o*tanh(f*c* + i*g) with preacts zs2[t] + w*
__global__ __launch_bounds__(256) void k_tail(
    const int* __restrict__ plen,
    const float2* __restrict__ zs2_all,
    const float2* __restrict__ wstar, const float* __restrict__ cstar,
    float* __restrict__ out)
{
    const int tid = blockIdx.x * 256 + threadIdx.x;
    if (tid >= L_PAD * 50) return;
    const int col = tid % 50;
    const int t   = tid / 50;
    const int len = *plen;
    if (t < len) return;
    const int d = col / HS;
    const int j = col % HS;

    const float2* __restrict__ z = zs2_all + (size_t)d * (L_PAD * 50);
    float2 zi = z[t * 50 + j];
    float2 zq = z[t * 50 + j + 25];
    float2 wi = wstar[d * 50 + j];
    float2 wq = wstar[d * 50 + j + 25];

    float i_ = fast_sigmoid(zi.x + wi.x);
    float g_ = fast_tanh  (zi.y + wi.y);
    float f_ = fast_sigmoid(zq.x + wq.x);
    float o_ = fast_sigmoid(zq.y + wq.y);

    float nc = fmaf(f_, cstar[d * HS + j], i_ * g_);
    out[t * 50 + col] = o_ * fast_tanh(nc);
}

extern "C" void kernel_launch(void* const* d_in, const int* in_sizes, int n_in,
                              void* d_out, int out_size, void* d_ws, size_t ws_size,
                              hipStream_t stream)
{
    const int*   tok  = (const int*)  d_in[0];
    const int*   plen = (const int*)  d_in[1];
    const float* Ef   = (const float*)d_in[2];
    const float* Wif  = (const float*)d_in[3];
    const float* Whf  = (const float*)d_in[4];
    const float* bf   = (const float*)d_in[5];
    const float* Eb   = (const float*)d_in[6];
    const float* Wib  = (const float*)d_in[7];
    const float* Whb  = (const float*)d_in[8];
    const float* bb   = (const float*)d_in[9];
    float* out = (float*)d_out;

    float2* zs2   = (float2*)d_ws;
    float2* wstar = (float2*)((char*)d_ws + (size_t)2 * L_PAD * 50 * sizeof(float2));
    float*  cstar = (float*)((char*)wstar + 100 * sizeof(float2));

    k_pre <<<2 * L_PAD, 64, 0, stream>>>(tok, plen, Ef, Wif, bf, Eb, Wib, bb, zs2);
    k_seq <<<2, 64, 0, stream>>>(Whf, Whb, plen, zs2, out, wstar, cstar);
    k_tail<<<(L_PAD * 50 + 255) / 256, 256, 0, stream>>>(plen, zs2, wstar, cstar, out);
}

// Round 3
// 2073.155 us; speedup vs baseline: 1.2811x; 1.2811x over previous
//
#include <hip/hip_runtime.h>

#define L_PAD 8192
#define HS    25
#define ES    50
#define G4    100   // 4*H
#define LOG2E 1.44269504088896340736f

// -------- workspace layout --------
// zs2   : float2[2][L_PAD*50]   packed gate preacts: zs2[d][t*50+j] = (z[j], z[j+50])
// wstar : float2[2][50]         h* @ Wh, same packing
// cstar : float [2][25]         frozen cell state

__device__ __forceinline__ float rl_f(float v, int lane) {
    return __int_as_float(__builtin_amdgcn_readlane(__float_as_int(v), lane));
}
__device__ __forceinline__ float fast_sigmoid(float x) {
    return __builtin_amdgcn_rcpf(1.f + __builtin_amdgcn_exp2f(x * (-LOG2E)));
}
__device__ __forceinline__ float fast_tanh(float x) {
    // 2*sigmoid(2x) - 1
    return fmaf(__builtin_amdgcn_rcpf(1.f + __builtin_amdgcn_exp2f(x * (-2.f * LOG2E))), 2.f, -1.f);
}

// ---------------- kernel 1: pre-activations (parallel) ----------------
__global__ __launch_bounds__(64) void k_pre(
    const int* __restrict__ tok, const int* __restrict__ plen,
    const float* __restrict__ Ef, const float* __restrict__ Wif, const float* __restrict__ bf,
    const float* __restrict__ Eb, const float* __restrict__ Wib, const float* __restrict__ bb,
    float2* __restrict__ zs2)
{
    const int b = blockIdx.x;
    const int d = b & 1;
    const int t = b >> 1;
    const int j = threadIdx.x;
    const int len = *plen;

    int src;
    if (d == 0) src = t;
    else        src = (t < len) ? (len - 1 - t) : (L_PAD - 1 - (t - len));
    const int token = tok[src];

    const float* __restrict__ E  = d ? Eb  : Ef;
    const float* __restrict__ Wi = d ? Wib : Wif;
    const float* __restrict__ bs = d ? bb  : bf;

    __shared__ float e[ES];
    if (j < ES) e[j] = E[(size_t)token * ES + j];
    __syncthreads();
    if (j >= 50) return;

    float ax = bs[j], ay = bs[j + 50];
    float bx = 0.f,  by = 0.f;
    #pragma unroll
    for (int k = 0; k < ES; k += 2) {
        float e0 = e[k], e1 = e[k + 1];
        ax = fmaf(e0, Wi[k * G4 + j],            ax);
        ay = fmaf(e0, Wi[k * G4 + j + 50],       ay);
        bx = fmaf(e1, Wi[(k + 1) * G4 + j],      bx);
        by = fmaf(e1, Wi[(k + 1) * G4 + j + 50], by);
    }
    zs2[(size_t)d * (L_PAD * 50) + t * 50 + j] = make_float2(ax + bx, ay + by);
}

// ---------------- kernel 2: the serial recurrence (latency-bound) ----------------
// one wave per direction. lane j in [0,50): gates (j, j+50).
//   lanes 0..24  -> (i_k, g_k),  lanes 25..49 -> (f_k, o_k)
// __launch_bounds__(64,1): ONE wave/EU -> register allocator may use the full
// VGPR file, keeping the 50-register W array resident (at (64) default it
// targeted high occupancy, VGPR_Count=36, and re-loaded W every iteration:
// ~700 stall cycles/step).
__global__ __launch_bounds__(64, 1) void k_seq(
    const float* __restrict__ Whf, const float* __restrict__ Whb,
    const int* __restrict__ plen,
    const float2* __restrict__ zs2_all,
    float* __restrict__ out,
    float2* __restrict__ wstar, float* __restrict__ cstar)
{
    const int d = blockIdx.x;
    const int j = threadIdx.x;
    const int len = *plen;
    const float* __restrict__ Wh = d ? Whb : Whf;
    const float2* __restrict__ z = zs2_all + (size_t)d * (L_PAD * 50);
    const int jj = (j < 50) ? j : 0;

    // Wh columns for my two gates, packed: 50 VGPRs, loop-invariant
    float2 W[HS];
    #pragma unroll
    for (int k = 0; k < HS; ++k)
        W[k] = make_float2(Wh[k * G4 + jj], Wh[k * G4 + jj + 50]);

    // branch-free activation constants: second gate is tanh for lanes<25, sigmoid otherwise
    const bool  isG = (j < 25);
    const float my = isG ? (-2.f * LOG2E) : (-LOG2E);
    const float ca = isG ? 2.f : 1.f;
    const float cb = isG ? -1.f : 0.f;

    float c = 0.f, h = 0.f;   // lanes 0..24 carry real state; other lanes' values never read
    const float2* __restrict__ zb = z + jj;
    float2 zc = zb[0];
    float2 zn = zb[50];
    float* outp = out + d * HS + j;   // stride 50 floats per step

    for (int t = 0; t < len; ++t) {
        int tp = t + 2; tp = (tp < L_PAD) ? tp : (L_PAD - 1);
        float2 zf = zb[tp * 50];                         // prefetch dist 2

        // z + h @ Wh  (4 accumulator chains to cut FMA dep latency)
        float2 a0 = zc;
        float2 a1 = make_float2(0.f, 0.f);
        float2 a2 = make_float2(0.f, 0.f);
        float2 a3 = make_float2(0.f, 0.f);
        #pragma unroll
        for (int k = 0; k < HS; k += 4) {
            float h0 = rl_f(h, k);
            a0.x = fmaf(h0, W[k].x, a0.x);
            a0.y = fmaf(h0, W[k].y, a0.y);
            if (k + 1 < HS) {
                float h1 = rl_f(h, k + 1);
                a1.x = fmaf(h1, W[k + 1].x, a1.x);
                a1.y = fmaf(h1, W[k + 1].y, a1.y);
            }
            if (k + 2 < HS) {
                float h2 = rl_f(h, k + 2);
                a2.x = fmaf(h2, W[k + 2].x, a2.x);
                a2.y = fmaf(h2, W[k + 2].y, a2.y);
            }
            if (k + 3 < HS) {
                float h3 = rl_f(h, k + 3);
                a3.x = fmaf(h3, W[k + 3].x, a3.x);
                a3.y = fmaf(h3, W[k + 3].y, a3.y);
            }
        }
        float px = (a0.x + a1.x) + (a2.x + a3.x);
        float py = (a0.y + a1.y) + (a2.y + a3.y);

        float sa = fast_sigmoid(px);                     // i (lanes<25) / f (lanes>=25)
        float ry = __builtin_amdgcn_rcpf(1.f + __builtin_amdgcn_exp2f(py * my));
        float sb = fmaf(ry, ca, cb);                     // g=tanh (lanes<25) / o=sigmoid

        float f_ = __shfl(sa, j + 25);                   // lane k reads lane k+25
        float o_ = __shfl(sb, j + 25);
        float nc = fmaf(f_, c, sa * sb);                 // f*c + i*g
        float nh = o_ * fast_tanh(nc);
        c = nc;                                          // unconditional: upper-lane
        h = nh;                                          //  garbage is never readlane'd
        if (j < 25) outp[t * 50] = nh;                   // out[t*50 + d*25 + j]
        zc = zn; zn = zf;
    }

    // epilogue: w* = h* @ Wh (packed) and c* for the frozen tail
    float2 a = make_float2(0.f, 0.f);
    #pragma unroll
    for (int k = 0; k < HS; ++k) {
        float hk = rl_f(h, k);
        a.x = fmaf(hk, W[k].x, a.x);
        a.y = fmaf(hk, W[k].y, a.y);
    }
    if (j < 50) wstar[d * 50 + j] = a;
    if (j < 25) cstar[d * HS + j] = c;
}

// ---------------- kernel 3: frozen-carry tail (parallel) ----------------
__global__ __launch_bounds__(256) void k_tail(
    const int* __restrict__ plen,
    const float2* __restrict__ zs2_all,
    const float2* __restrict__ wstar, const float* __restrict__ cstar,
    float* __restrict__ out)
{
    const int tid = blockIdx.x * 256 + threadIdx.x;
    if (tid >= L_PAD * 50) return;
    const int col = tid % 50;
    const int t   = tid / 50;
    const int len = *plen;
    if (t < len) return;
    const int d = col / HS;
    const int j = col % HS;

    const float2* __restrict__ z = zs2_all + (size_t)d * (L_PAD * 50);
    float2 zi = z[t * 50 + j];
    float2 zq = z[t * 50 + j + 25];
    float2 wi = wstar[d * 50 + j];
    float2 wq = wstar[d * 50 + j + 25];

    float i_ = fast_sigmoid(zi.x + wi.x);
    float g_ = fast_tanh  (zi.y + wi.y);
    float f_ = fast_sigmoid(zq.x + wq.x);
    float o_ = fast_sigmoid(zq.y + wq.y);

    float nc = fmaf(f_, cstar[d * HS + j], i_ * g_);
    out[t * 50 + col] = o_ * fast_tanh(nc);
}

extern "C" void kernel_launch(void* const* d_in, const int* in_sizes, int n_in,
                              void* d_out, int out_size, void* d_ws, size_t ws_size,
                              hipStream_t stream)
{
    const int*   tok  = (const int*)  d_in[0];
    const int*   plen = (const int*)  d_in[1];
    const float* Ef   = (const float*)d_in[2];
    const float* Wif  = (const float*)d_in[3];
    const float* Whf  = (const float*)d_in[4];
    const float* bf   = (const float*)d_in[5];
    const float* Eb   = (const float*)d_in[6];
    const float* Wib  = (const float*)d_in[7];
    const float* Whb  = (const float*)d_in[8];
    const float* bb   = (const float*)d_in[9];
    float* out = (float*)d_out;

    float2* zs2   = (float2*)d_ws;
    float2* wstar = (float2*)((char*)d_ws + (size_t)2 * L_PAD * 50 * sizeof(float2));
    float*  cstar = (float*)((char*)wstar + 100 * sizeof(float2));

    k_pre <<<2 * L_PAD, 64, 0, stream>>>(tok, plen, Ef, Wif, bf, Eb, Wib, bb, zs2);
    k_seq <<<2, 64, 0, stream>>>(Whf, Whb, plen, zs2, out, wstar, cstar);
    k_tail<<<(L_PAD * 50 + 255) / 256, 256, 0, stream>>>(plen, zs2, wstar, cstar, out);
}